// Round 6
// baseline (175.670 us; speedup 1.0000x reference)
//
#include <hip/hip_runtime.h>
#include <hip/hip_cooperative_groups.h>

namespace cg = cooperative_groups;

#define KOBJ  128
#define QMIN  0.5f
#define SB    1.0f
#define BDIM  256
#define NSCB  64            // blocks per batch element (scan & pairs)
#define BATCH 8
#define GRID  (NSCB * BATCH)   // 512 blocks

typedef unsigned long long u64;
typedef unsigned int u32;

// ---- workspace layout (bytes); NO zero-init required (plain stores only) ----
// 0      : u64  pkey [GRID][KOBJ]   524288 B   per-block argmax partial keys
// 524288 : f32  nsp  [GRID]           2048 B   per-block noise-beta partials
// 526336 : u32  ncp  [GRID]           2048 B   per-block noise count partials
// 528384 : f4   xaq  [BATCH][KOBJ]   16384 B   {x_a, y_a, q_a*present, 0}
// 544768 : f32  terms[BATCH]            32 B   L_beta + L_noise per batch
// 544800 : f32  qsum [BATCH]            32 B   sum of q_a*present
// 544832 : f32  pairp[GRID]           2048 B   per-block pair partials
struct WS { u64* pkey; float* nsp; u32* ncp; float4* xaq; float* terms; float* qsum; float* pairp; };
__device__ __forceinline__ WS wsmap(void* w_) {
    char* w = (char*)w_;
    WS s;
    s.pkey  = (u64*)(w);
    s.nsp   = (float*)(w + 524288);
    s.ncp   = (u32*)(w + 526336);
    s.xaq   = (float4*)(w + 528384);
    s.terms = (float*)(w + 544768);
    s.qsum  = (float*)(w + 544800);
    s.pairp = (float*)(w + 544832);
    return s;
}

__device__ __forceinline__ float waveRedF(float v) {
    #pragma unroll
    for (int o = 32; o; o >>= 1) v += __shfl_down(v, o, 64);
    return v;
}
__device__ __forceinline__ unsigned int waveRedU(unsigned int v) {
    #pragma unroll
    for (int o = 32; o; o >>= 1) v += __shfl_down(v, o, 64);
    return v;
}

// ---------------- phase 1: per-block argmax scan + noise partials ----------------
__device__ __forceinline__ void scan_phase(const float* __restrict__ beta,
                                           const int* __restrict__ tix,
                                           const WS& S, int N, int bx, int tid,
                                           u64* skey) {
    const int b = bx / NSCB, sub = bx % NSCB;
    const int chunk = (N + NSCB - 1) / NSCB;
    const int n0 = sub * chunk, n1 = min(n0 + chunk, N);

    for (int i = tid; i < KOBJ; i += BDIM) skey[i] = 0ull;
    __syncthreads();

    float ns = 0.f; u32 nc = 0u;
    for (int n = n0 + tid; n < n1; n += BDIM) {
        const float bc = fminf(fmaxf(beta[(size_t)b * N + n], 1e-6f), 1.0f - 1e-5f);
        const int t = tix[(size_t)b * N + n];
        const u64 kk = ((u64)__float_as_uint(bc) << 32) | (u64)(~(u32)n);  // ties -> min n
        atomicMax(&skey[t], kk);                                            // LDS atomic
        if (t == 0) { ns += bc; nc++; }
    }
    __syncthreads();
    if (tid < KOBJ) S.pkey[(size_t)bx * KOBJ + tid] = skey[tid];

    ns = waveRedF(ns); nc = waveRedU(nc);
    __shared__ float s_f[BDIM / 64];
    __shared__ u32   s_u[BDIM / 64];
    if ((tid & 63) == 0) { s_f[tid >> 6] = ns; s_u[tid >> 6] = nc; }
    __syncthreads();
    if (tid == 0) {
        float a = 0.f; u32 c = 0u;
        #pragma unroll
        for (int w = 0; w < BDIM / 64; ++w) { a += s_f[w]; c += s_u[w]; }
        S.nsp[bx] = a; S.ncp[bx] = c;
    }
    __syncthreads();
}

// ---------------- phase 2: reduce partials -> alpha tables + terms ----------------
__device__ __forceinline__ void reduce_phase(const float* __restrict__ cc,
                                             const WS& S, int N, int b, int tid) {
    float lb = 0.f, qe = 0.f;
    u32 pc = 0u;
    if (tid < KOBJ) {
        u64 kv = 0ull;
        #pragma unroll 8
        for (int s = 0; s < NSCB; ++s) {
            const u64 v = S.pkey[(size_t)(b * NSCB + s) * KOBJ + tid];
            kv = v > kv ? v : kv;
        }
        const bool present = (kv != 0ull) && (tid > 0);
        float x = 0.f, y = 0.f, qv = 0.f;
        if (kv != 0ull) {
            const u32 na = ~(u32)(kv & 0xFFFFFFFFull);
            const float ba = __uint_as_float((u32)(kv >> 32));
            const float2 xy = *(const float2*)&cc[((size_t)b * N + na) * 2];
            x = xy.x; y = xy.y;
            const float a = atanhf(ba / 1.002f);
            qv = a * a + QMIN;
            if (present) { lb = 1.f - ba; pc = 1u; }
        }
        qe = present ? qv : 0.f;
        S.xaq[(size_t)b * KOBJ + tid] = make_float4(x, y, qe, 0.f);
    }
    float ns = 0.f; u32 nc = 0u;
    if (tid < NSCB) { ns = S.nsp[b * NSCB + tid]; nc = S.ncp[b * NSCB + tid]; }

    lb = waveRedF(lb); pc = waveRedU(pc);
    ns = waveRedF(ns); nc = waveRedU(nc);
    float qs = waveRedF(qe);
    __shared__ float s_lb[BDIM / 64], s_ns[BDIM / 64], s_qs[BDIM / 64];
    __shared__ u32   s_pc[BDIM / 64], s_nc[BDIM / 64];
    const int wv = tid >> 6;
    if ((tid & 63) == 0) { s_lb[wv] = lb; s_pc[wv] = pc; s_ns[wv] = ns; s_nc[wv] = nc; s_qs[wv] = qs; }
    __syncthreads();
    if (tid == 0) {
        float L = 0.f, A = 0.f, Q = 0.f; u32 P = 0u, C = 0u;
        #pragma unroll
        for (int w = 0; w < BDIM / 64; ++w) { L += s_lb[w]; P += s_pc[w]; A += s_ns[w]; C += s_nc[w]; Q += s_qs[w]; }
        S.terms[b] = L / (float)max(P, 1u) + SB * A / (float)max(C, 1u);
        S.qsum[b]  = Q;
    }
    __syncthreads();
}

// ---------------- phase 3: O(N*K) pair potentials ----------------
__device__ __forceinline__ void pairs_phase(const float* __restrict__ cc,
                                            const float* __restrict__ beta,
                                            const int* __restrict__ tix,
                                            const WS& S, int N, int bx, int tid,
                                            float2* sxy, float* sqv) {
    const int b = bx / NSCB, sub = bx % NSCB;
    const int chunk = (N + NSCB - 1) / NSCB;
    const int n0 = sub * chunk, n1 = min(n0 + chunk, N);

    if (tid < KOBJ) {
        const float4 v = S.xaq[(size_t)b * KOBJ + tid];
        sxy[tid] = make_float2(v.x, v.y);
        sqv[tid] = v.z;
    }
    __syncthreads();
    const float qs = S.qsum[b];

    float acc_tot = 0.f;
    for (int n = n0 + tid; n < n1; n += BDIM) {
        const float2 xy = *(const float2*)&cc[((size_t)b * N + n) * 2];
        const float bc = fminf(fmaxf(beta[(size_t)b * N + n], 1e-6f), 1.0f - 1e-5f);
        const int t = tix[(size_t)b * N + n];
        const float a = atanhf(bc / 1.002f);
        const float qn = a * a + QMIN;
        float acc = 0.f;                       // sum_k q_k * min(d_k, 1)
        #pragma unroll 8
        for (int k = 0; k < KOBJ; ++k) {
            const float dx = xy.x - sxy[k].x;
            const float dy = xy.y - sxy[k].y;
            const float d2e = fmaf(dy, dy, fmaf(dx, dx, 1e-6f));
            const float d = sqrtf(d2e);
            acc = fmaf(sqv[k], fminf(d, 1.f), acc);
        }
        // sum_k q_k*max(0,1-d_k) = qs - acc; patch k==t: attractive d2 instead
        const float2 st = sxy[t];
        const float dxt = xy.x - st.x;
        const float dyt = xy.y - st.y;
        const float d2et = fmaf(dyt, dyt, fmaf(dxt, dxt, 1e-6f));
        const float dt = sqrtf(d2et);
        const float point = qs - acc + sqv[t] * ((d2et - 1e-6f) - 1.f + fminf(dt, 1.f));
        acc_tot += point * qn;
    }

    acc_tot = waveRedF(acc_tot);
    __shared__ float s_a[BDIM / 64];
    if ((tid & 63) == 0) s_a[tid >> 6] = acc_tot;
    __syncthreads();
    if (tid == 0) {
        float s = 0.f;
        #pragma unroll
        for (int w = 0; w < BDIM / 64; ++w) s += s_a[w];
        S.pairp[bx] = s;
    }
    __syncthreads();
}

// ---------------- phase 4: final combine ----------------
__device__ __forceinline__ void final_phase(const WS& S, float* __restrict__ out,
                                            int N, int tid) {
    float p = 0.f;
    for (int i = tid; i < GRID; i += BDIM) p += S.pairp[i];
    p = waveRedF(p);
    __shared__ float s_p[BDIM / 64];
    if ((tid & 63) == 0) s_p[tid >> 6] = p;
    float t8 = (tid < BATCH) ? S.terms[tid] : 0.f;   // wave 0 only
    t8 = waveRedF(t8);
    __syncthreads();
    if (tid == 0) {
        float P = 0.f;
        #pragma unroll
        for (int w = 0; w < BDIM / 64; ++w) P += s_p[w];
        out[0] = (P / (float)N + t8) / (float)BATCH;
    }
}

// ================= cooperative single-dispatch kernel =================
__global__ void __launch_bounds__(BDIM, 4)
oc_coop(const float* __restrict__ cc, const float* __restrict__ beta,
        const int* __restrict__ tix, float* __restrict__ out,
        void* __restrict__ wsv, int N) {
    WS S = wsmap(wsv);
    __shared__ u64    skey[KOBJ];
    __shared__ float2 sxy[KOBJ];
    __shared__ float  sqv[KOBJ];
    cg::grid_group g = cg::this_grid();
    const int bx = blockIdx.x, tid = threadIdx.x;

    scan_phase(beta, tix, S, N, bx, tid, skey);
    g.sync();
    if (bx < BATCH) reduce_phase(cc, S, N, bx, tid);
    g.sync();
    pairs_phase(cc, beta, tix, S, N, bx, tid, sxy, sqv);
    g.sync();
    if (bx == 0) final_phase(S, out, N, tid);
}

// ================= fallback: same phases, 4 dispatches =================
__global__ void __launch_bounds__(BDIM, 4)
oc_scan_k(const float* __restrict__ beta, const int* __restrict__ tix,
          void* __restrict__ wsv, int N) {
    WS S = wsmap(wsv);
    __shared__ u64 skey[KOBJ];
    scan_phase(beta, tix, S, N, blockIdx.x, threadIdx.x, skey);
}
__global__ void __launch_bounds__(BDIM, 4)
oc_reduce_k(const float* __restrict__ cc, void* __restrict__ wsv, int N) {
    WS S = wsmap(wsv);
    reduce_phase(cc, S, N, blockIdx.x, threadIdx.x);
}
__global__ void __launch_bounds__(BDIM, 4)
oc_pairs_k(const float* __restrict__ cc, const float* __restrict__ beta,
           const int* __restrict__ tix, void* __restrict__ wsv, int N) {
    WS S = wsmap(wsv);
    __shared__ float2 sxy[KOBJ];
    __shared__ float  sqv[KOBJ];
    pairs_phase(cc, beta, tix, S, N, blockIdx.x, threadIdx.x, sxy, sqv);
}
__global__ void __launch_bounds__(BDIM, 4)
oc_final_k(void* __restrict__ wsv, float* __restrict__ out, int N) {
    WS S = wsmap(wsv);
    final_phase(S, out, N, threadIdx.x);
}

extern "C" void kernel_launch(void* const* d_in, const int* in_sizes, int n_in,
                              void* d_out, int out_size, void* d_ws, size_t ws_size,
                              hipStream_t stream) {
    const float* cc   = (const float*)d_in[0];   // (B,N,2) f32
    const float* beta = (const float*)d_in[1];   // (B,N)   f32
    const int*   tix  = (const int*)d_in[2];     // (B,N)   i32
    float* out = (float*)d_out;
    int N = in_sizes[1] / BATCH;
    void* wsv = d_ws;

    void* args[] = { (void*)&cc, (void*)&beta, (void*)&tix,
                     (void*)&out, (void*)&wsv, (void*)&N };
    hipError_t e = hipLaunchCooperativeKernel(reinterpret_cast<void*>(oc_coop),
                                              dim3(GRID), dim3(BDIM), args, 0, stream);
    if (e != hipSuccess) {
        (void)hipGetLastError();   // clear sticky error, take the 4-dispatch path
        oc_scan_k  <<<dim3(GRID),  BDIM, 0, stream>>>(beta, tix, wsv, N);
        oc_reduce_k<<<dim3(BATCH), BDIM, 0, stream>>>(cc, wsv, N);
        oc_pairs_k <<<dim3(GRID),  BDIM, 0, stream>>>(cc, beta, tix, wsv, N);
        oc_final_k <<<dim3(1),     BDIM, 0, stream>>>(wsv, out, N);
    }
}

// Round 7
// 42.731 us; speedup vs baseline: 4.1111x; 4.1111x over previous
//
#include <hip/hip_runtime.h>

#define KOBJ  128
#define QMIN  0.5f
#define SB    1.0f
#define BDIM  256
#define NSCB  128           // scan blocks per batch element
#define BATCH 8
#define PPB   256           // points per pairs-block (1 per thread)

typedef unsigned long long u64;
typedef unsigned int u32;

// ---- workspace layout (bytes); NO zero-init required (plain stores only) ----
// 0       : u64  pkey [BATCH*NSCB][KOBJ]  1048576 B  per-block argmax partial keys
// 1048576 : f32  nsp  [BATCH*NSCB]           4096 B  per-block noise-beta partials
// 1052672 : u32  ncp  [BATCH*NSCB]           4096 B  per-block noise count partials
// 1056768 : f4   xaq  [BATCH][KOBJ]         16384 B  {x_a, y_a, q_a*present, 0}
// 1073152 : f32  qsum [BATCH]                  32 B  sum of q_a*present
// total 1073184 B

__device__ __forceinline__ float waveRedF(float v) {
    #pragma unroll
    for (int o = 32; o; o >>= 1) v += __shfl_down(v, o, 64);
    return v;
}
__device__ __forceinline__ u32 waveRedU(u32 v) {
    #pragma unroll
    for (int o = 32; o; o >>= 1) v += __shfl_down(v, o, 64);
    return v;
}

// ---------- dispatch 1: per-block argmax scan + noise partials; zero out[0] ----------
__global__ void __launch_bounds__(BDIM)
oc_scan(const float* __restrict__ beta, const int* __restrict__ t_idx,
        u64* __restrict__ pkey, float* __restrict__ nsp, u32* __restrict__ ncp,
        float* __restrict__ out, int N) {
    const int tid = threadIdx.x;
    const int b   = blockIdx.y;
    const int sub = blockIdx.x;
    const int bid = b * NSCB + sub;
    const int chunk = (N + NSCB - 1) / NSCB;
    const int n0 = sub * chunk;
    const int n1 = min(n0 + chunk, N);

    if (bid == 0 && tid == 0) out[0] = 0.f;      // fresh accumulator each call

    __shared__ u64 skey[KOBJ];
    if (tid < KOBJ) skey[tid] = 0ull;
    __syncthreads();

    float ns = 0.f;
    u32 nc = 0u;
    for (int n = n0 + tid; n < n1; n += BDIM) {
        const float bc = fminf(fmaxf(beta[(size_t)b * N + n], 1e-6f), 1.0f - 1e-5f);
        const int t = t_idx[(size_t)b * N + n];
        const u64 kk = ((u64)__float_as_uint(bc) << 32) | (u64)(~(u32)n);  // ties -> min n
        atomicMax(&skey[t], kk);                                            // LDS atomic
        if (t == 0) { ns += bc; nc++; }
    }
    __syncthreads();
    if (tid < KOBJ) pkey[(size_t)bid * KOBJ + tid] = skey[tid];

    ns = waveRedF(ns);
    nc = waveRedU(nc);
    __shared__ float s_ns[BDIM / 64];
    __shared__ u32   s_nc[BDIM / 64];
    if ((tid & 63) == 0) { s_ns[tid >> 6] = ns; s_nc[tid >> 6] = nc; }
    __syncthreads();
    if (tid == 0) {
        float a = 0.f; u32 c = 0u;
        #pragma unroll
        for (int w = 0; w < BDIM / 64; ++w) { a += s_ns[w]; c += s_nc[w]; }
        nsp[bid] = a; ncp[bid] = c;
    }
}

// ---------- dispatch 2: collapse partials -> alpha table; add (L_beta+L_noise)/B ----------
__global__ void __launch_bounds__(KOBJ)
oc_reduce(const float* __restrict__ cc, const u64* __restrict__ pkey,
          const float* __restrict__ nsp, const u32* __restrict__ ncp,
          float4* __restrict__ xaq, float* __restrict__ qsum,
          float* __restrict__ out, int N) {
    const int b = blockIdx.x;
    const int k = threadIdx.x;          // 128 threads

    u64 kv = 0ull;
    #pragma unroll 8
    for (int s = 0; s < NSCB; ++s) {
        const u64 v = pkey[(size_t)(b * NSCB + s) * KOBJ + k];
        kv = v > kv ? v : kv;
    }
    const bool present = (kv != 0ull) && (k > 0);
    float x = 0.f, y = 0.f, qv = 0.f, lb = 0.f;
    u32 pc = 0u;
    if (kv != 0ull) {
        const u32 na = ~(u32)(kv & 0xFFFFFFFFull);
        const float ba = __uint_as_float((u32)(kv >> 32));
        const float2 xy = *(const float2*)&cc[((size_t)b * N + na) * 2];
        x = xy.x; y = xy.y;
        const float a = atanhf(ba / 1.002f);
        qv = a * a + QMIN;
        if (present) { lb = 1.f - ba; pc = 1u; }
    }
    const float qe = present ? qv : 0.f;
    xaq[(size_t)b * KOBJ + k] = make_float4(x, y, qe, 0.f);

    // noise partials: one per thread (NSCB == KOBJ == 128)
    float ns = nsp[b * NSCB + k];
    u32   nc = ncp[b * NSCB + k];

    lb = waveRedF(lb);  pc = waveRedU(pc);
    ns = waveRedF(ns);  nc = waveRedU(nc);
    float qs = waveRedF(qe);
    __shared__ float s_lb[2], s_ns[2], s_qs[2];
    __shared__ u32   s_pc[2], s_nc[2];
    const int wv = k >> 6;
    if ((k & 63) == 0) { s_lb[wv] = lb; s_pc[wv] = pc; s_ns[wv] = ns; s_nc[wv] = nc; s_qs[wv] = qs; }
    __syncthreads();
    if (k == 0) {
        const float L = s_lb[0] + s_lb[1];
        const u32   P = s_pc[0] + s_pc[1];
        const float A = s_ns[0] + s_ns[1];
        const u32   C = s_nc[0] + s_nc[1];
        qsum[b] = s_qs[0] + s_qs[1];
        const float terms = L / (float)max(P, 1u) + SB * A / (float)max(C, 1u);
        atomicAdd(out, terms * (1.f / (float)BATCH));   // out zeroed in dispatch 1
    }
}

// ---------- dispatch 3: O(N*K) pair potentials; atomic-accumulate into out ----------
__global__ void __launch_bounds__(PPB)
oc_pairs(const float* __restrict__ cc, const float* __restrict__ beta,
         const int* __restrict__ t_idx,
         const float4* __restrict__ xaq, const float* __restrict__ qsum,
         float* __restrict__ out, int N, float invNB) {
    const int tid = threadIdx.x;
    const int b   = blockIdx.y;
    const int sub = blockIdx.x;
    const int n   = sub * PPB + tid;

    const float4* __restrict__ tab = xaq + (size_t)b * KOBJ;   // uniform per block

    float acc_tot = 0.f;
    if (n < N) {
        const float2 xy = *(const float2*)&cc[((size_t)b * N + n) * 2];
        const float bc = fminf(fmaxf(beta[(size_t)b * N + n], 1e-6f), 1.0f - 1e-5f);
        const int t = t_idx[(size_t)b * N + n];
        const float a = atanhf(bc / 1.002f);
        const float qn = a * a + QMIN;
        float acc = 0.f;                       // sum_k q_k * min(d_k, 1)
        #pragma unroll 8
        for (int k = 0; k < KOBJ; ++k) {
            const float4 T = tab[k];           // uniform address -> scalar load
            const float dx = xy.x - T.x;
            const float dy = xy.y - T.y;
            const float d2e = fmaf(dy, dy, fmaf(dx, dx, 1e-6f));
            const float d = sqrtf(d2e);
            acc = fmaf(T.z, fminf(d, 1.f), acc);
        }
        // sum_k q_k*max(0,1-d_k) = qsum - acc; patch k==t: attractive d2 instead
        const float4 Tt = tab[t];
        const float dxt = xy.x - Tt.x;
        const float dyt = xy.y - Tt.y;
        const float d2et = fmaf(dyt, dyt, fmaf(dxt, dxt, 1e-6f));
        const float dt = sqrtf(d2et);
        const float point = qsum[b] - acc + Tt.z * ((d2et - 1e-6f) - 1.f + fminf(dt, 1.f));
        acc_tot = point * qn;
    }

    acc_tot = waveRedF(acc_tot);
    __shared__ float s_a[PPB / 64];
    if ((tid & 63) == 0) s_a[tid >> 6] = acc_tot;
    __syncthreads();
    if (tid == 0) {
        float s = 0.f;
        #pragma unroll
        for (int w = 0; w < PPB / 64; ++w) s += s_a[w];
        atomicAdd(out, s * invNB);             // device-scope, no fence needed
    }
}

extern "C" void kernel_launch(void* const* d_in, const int* in_sizes, int n_in,
                              void* d_out, int out_size, void* d_ws, size_t ws_size,
                              hipStream_t stream) {
    const float* cc   = (const float*)d_in[0];   // (B,N,2) f32
    const float* beta = (const float*)d_in[1];   // (B,N)   f32
    const int*   tix  = (const int*)d_in[2];     // (B,N)   i32
    float* out = (float*)d_out;
    const int N = in_sizes[1] / BATCH;

    char* ws = (char*)d_ws;
    u64*    pkey = (u64*)(ws + 0);
    float*  nsp  = (float*)(ws + 1048576);
    u32*    ncp  = (u32*)(ws + 1052672);
    float4* xaq  = (float4*)(ws + 1056768);
    float*  qsum = (float*)(ws + 1073152);

    const int nppb = (N + PPB - 1) / PPB;        // pairs blocks per batch
    const float invNB = 1.f / ((float)N * (float)BATCH);

    oc_scan  <<<dim3(NSCB, BATCH), BDIM, 0, stream>>>(beta, tix, pkey, nsp, ncp, out, N);
    oc_reduce<<<dim3(BATCH), KOBJ, 0, stream>>>(cc, pkey, nsp, ncp, xaq, qsum, out, N);
    oc_pairs <<<dim3(nppb, BATCH), PPB, 0, stream>>>(cc, beta, tix, xaq, qsum, out, N, invNB);
}